// Round 1
// baseline (346.202 us; speedup 1.0000x reference)
//
#include <hip/hip_runtime.h>
#include <math.h>

#define NN 20000
#define EE 320000
#define E2 340000   // EE + NN self loops
#define GG 64

// ---------------- prep: collapse edge-attention vectors ----------------
// ve1[h][i] = sum_c We1[i*32 + h*16 + c] * ae1[h*16+c]   -> params[h*2+i]
// ve2[i]   = sum_c We2[i*256 + c] * ae2[c]               -> params[4+i]
__global__ void k_prep(const float* We1, const float* ae1,
                       const float* We2, const float* ae2, float* params) {
    int t = threadIdx.x;  // 64 threads, 1 wave
    float p0 = 0.f, p1 = 0.f;
    for (int c = t; c < 256; c += 64) {
        float a = ae2[c];
        p0 += We2[c] * a;
        p1 += We2[256 + c] * a;
    }
    for (int m = 32; m >= 1; m >>= 1) { p0 += __shfl_xor(p0, m); p1 += __shfl_xor(p1, m); }
    if (t == 0) { params[4] = p0; params[5] = p1; }
    int h = t >> 5, i = (t >> 4) & 1, c = t & 15;
    float p = We1[i * 32 + h * 16 + c] * ae1[h * 16 + c];
    for (int m = 8; m >= 1; m >>= 1) p += __shfl_xor(p, m);
    if ((t & 15) == 0) params[h * 2 + i] = p;
}

// ---------------- mean of edge_attr over E edges ----------------
__global__ void k_meansum(const float* ea, float* meansum) {
    __shared__ float s0[4], s1[4];
    int gid = blockIdx.x * blockDim.x + threadIdx.x;
    int stride = gridDim.x * blockDim.x;
    float a0 = 0.f, a1 = 0.f;
    const float2* ea2 = (const float2*)ea;
    for (int e = gid; e < EE; e += stride) { float2 v = ea2[e]; a0 += v.x; a1 += v.y; }
    for (int m = 32; m >= 1; m >>= 1) { a0 += __shfl_xor(a0, m); a1 += __shfl_xor(a1, m); }
    int lane = threadIdx.x & 63, w = threadIdx.x >> 6;
    if (lane == 0) { s0[w] = a0; s1[w] = a1; }
    __syncthreads();
    if (threadIdx.x == 0) {
        float t0 = s0[0] + s0[1] + s0[2] + s0[3];
        float t1 = s1[0] + s1[1] + s1[2] + s1[3];
        atomicAdd(&meansum[0], t0);
        atomicAdd(&meansum[1], t1);
    }
}

// ---------------- degree histogram over dst ----------------
__global__ void k_deg(const int* ei, int* deg) {
    int t = blockIdx.x * 256 + threadIdx.x;
    if (t >= E2) return;
    int dst = (t < EE) ? ei[EE + t] : (t - EE);
    atomicAdd(&deg[dst], 1);
}

// ---------------- single-block exclusive scan -> rowptr ----------------
__global__ void k_scan(const int* deg, int* rowptr) {
    __shared__ int wsum[16];
    __shared__ int carry;
    int t = threadIdx.x;
    if (t == 0) carry = 0;
    __syncthreads();
    for (int base = 0; base < NN; base += 1024) {
        int i = base + t;
        int v = (i < NN) ? deg[i] : 0;
        int x = v;
        for (int off = 1; off < 64; off <<= 1) {
            int y = __shfl_up(x, off);
            if ((t & 63) >= off) x += y;
        }
        if ((t & 63) == 63) wsum[t >> 6] = x;
        __syncthreads();
        if (t < 16) {
            int s = wsum[t];
            for (int off = 1; off < 16; off <<= 1) {
                int y = __shfl_up(s, off);
                if (t >= off) s += y;
            }
            wsum[t] = s;
        }
        __syncthreads();
        int pre = (t >= 64) ? wsum[(t >> 6) - 1] : 0;
        int incl = x + pre + carry;
        if (i < NN) rowptr[i] = incl - v;
        if (i == NN - 1) rowptr[NN] = incl;
        __syncthreads();
        if (t == 1023) carry = incl;
        __syncthreads();
    }
}

// ---------------- CSR fill (src + reordered edge_attr) ----------------
__global__ void k_fill(const int* ei, const float* ea, const float* meansum,
                       const int* rowptr, int* cursor, int* csr_src, float* csr_ea) {
    int t = blockIdx.x * 256 + threadIdx.x;
    if (t >= E2) return;
    int src, dst; float e0, e1;
    if (t < EE) {
        src = ei[t]; dst = ei[EE + t];
        float2 v = ((const float2*)ea)[t];
        e0 = v.x; e1 = v.y;
    } else {
        src = dst = t - EE;
        const float inv = 1.0f / (float)EE;
        e0 = meansum[0] * inv; e1 = meansum[1] * inv;
    }
    int pos = rowptr[dst] + atomicAdd(&cursor[dst], 1);
    csr_src[pos] = src;
    ((float2*)csr_ea)[pos] = make_float2(e0, e1);
}

// ---------------- graph boundaries (batch is sorted) ----------------
__global__ void k_gs(const int* batch, int* gs) {
    int g = threadIdx.x;
    if (g > GG) return;
    if (g == GG) { gs[GG] = NN; return; }
    int lo = 0, hi = NN;
    while (lo < hi) { int mid = (lo + hi) >> 1; if (batch[mid] < g) lo = mid + 1; else hi = mid; }
    gs[g] = lo;
}

// ---------------- layer 1: h1 = x @ W1 ; a_s1, a_d1 ----------------
__global__ void k_h1(const float* x, const float* W1, const float* as1, const float* ad1,
                     float* h1, float* a_s1, float* a_d1) {
    int gid = blockIdx.x * 256 + threadIdx.x;
    if (gid >= NN * 32) return;
    int n = gid >> 5, c = gid & 31;
    float4 xv = ((const float4*)x)[n];
    float acc = xv.x * W1[c] + xv.y * W1[32 + c] + xv.z * W1[64 + c] + xv.w * W1[96 + c];
    h1[gid] = acc;
    float ps = acc * as1[c], pd = acc * ad1[c];
    for (int m = 8; m >= 1; m >>= 1) { ps += __shfl_xor(ps, m); pd += __shfl_xor(pd, m); }
    if ((c & 15) == 0) { int h = c >> 4; a_s1[n * 2 + h] = ps; a_d1[n * 2 + h] = pd; }
}

// ---------------- layer 1 segment softmax ----------------
__global__ void k_soft1(const int* rowptr, const int* csr_src, const float* csr_ea,
                        const float* a_s1, const float* a_d1, const float* params, float* w1) {
    int t = blockIdx.x * 256 + threadIdx.x;
    if (t >= 2 * NN) return;
    int d = t >> 1, h = t & 1;
    int rs = rowptr[d], re = rowptr[d + 1];
    float ad = a_d1[d * 2 + h];
    float vx = params[h * 2 + 0], vy = params[h * 2 + 1];
    float mx = -1e30f;
    for (int p = rs; p < re; p++) {
        int s = csr_src[p];
        float2 e = ((const float2*)csr_ea)[p];
        float al = a_s1[s * 2 + h] + ad + e.x * vx + e.y * vy;
        al = al > 0.f ? al : 0.2f * al;
        w1[p * 2 + h] = al;
        mx = fmaxf(mx, al);
    }
    float sum = 0.f;
    for (int p = rs; p < re; p++) {
        float ex = __expf(w1[p * 2 + h] - mx);
        w1[p * 2 + h] = ex;
        sum += ex;
    }
    float r = 1.0f / (sum + 1e-16f);
    for (int p = rs; p < re; p++) w1[p * 2 + h] *= r;
}

// ---------------- layer 1 aggregation + bias + relu ----------------
__global__ void k_agg1(const int* rowptr, const int* csr_src, const float* w1,
                       const float* h1, const float* b1, float* h1o) {
    int gid = blockIdx.x * 256 + threadIdx.x;
    int n = gid >> 5, c = gid & 31, h = c >> 4;
    if (n >= NN) return;
    int rs = rowptr[n], re = rowptr[n + 1];
    float acc = 0.f;
    for (int p = rs; p < re; p++) {
        int s = csr_src[p];
        acc += w1[p * 2 + h] * h1[s * 32 + c];
    }
    float o = acc + b1[c];
    h1o[gid] = fmaxf(o, 0.f);
}

// ---------------- layer 2 dense: h2 = h1o @ W2  (16 nodes / block) ----------------
__global__ void __launch_bounds__(256) k_h2(const float* h1o, const float* W2, float* h2) {
    __shared__ float sh[512];
    int tid = threadIdx.x;
    int n0 = blockIdx.x * 16;
    for (int k = tid; k < 512; k += 256) sh[k] = h1o[n0 * 32 + k];
    __syncthreads();
    float w[32];
#pragma unroll
    for (int i = 0; i < 32; i++) w[i] = W2[i * 256 + tid];
#pragma unroll 4
    for (int m = 0; m < 16; m++) {
        float acc = 0.f;
#pragma unroll
        for (int i = 0; i < 32; i++) acc += sh[m * 32 + i] * w[i];
        h2[(size_t)(n0 + m) * 256 + tid] = acc;
    }
}

// ---------------- layer 2 attention coefficients per node ----------------
__global__ void k_att2(const float* h2, const float* as2, const float* ad2,
                       float* a_s2, float* a_d2) {
    int gid = blockIdx.x * 256 + threadIdx.x;
    int n = gid >> 6, lane = gid & 63;
    if (n >= NN) return;
    const float* row = h2 + (size_t)n * 256;
    float ps = 0.f, pd = 0.f;
#pragma unroll
    for (int j = 0; j < 4; j++) {
        int c = lane + 64 * j;
        float v = row[c];
        ps += v * as2[c];
        pd += v * ad2[c];
    }
    for (int m = 32; m >= 1; m >>= 1) { ps += __shfl_xor(ps, m); pd += __shfl_xor(pd, m); }
    if (lane == 0) { a_s2[n] = ps; a_d2[n] = pd; }
}

// ---------------- layer 2 segment softmax ----------------
__global__ void k_soft2(const int* rowptr, const int* csr_src, const float* csr_ea,
                        const float* a_s2, const float* a_d2, const float* params, float* w2) {
    int d = blockIdx.x * 256 + threadIdx.x;
    if (d >= NN) return;
    int rs = rowptr[d], re = rowptr[d + 1];
    float ad = a_d2[d];
    float vx = params[4], vy = params[5];
    float mx = -1e30f;
    for (int p = rs; p < re; p++) {
        int s = csr_src[p];
        float2 e = ((const float2*)csr_ea)[p];
        float al = a_s2[s] + ad + e.x * vx + e.y * vy;
        al = al > 0.f ? al : 0.2f * al;
        w2[p] = al;
        mx = fmaxf(mx, al);
    }
    float sum = 0.f;
    for (int p = rs; p < re; p++) { float ex = __expf(w2[p] - mx); w2[p] = ex; sum += ex; }
    float r = 1.0f / (sum + 1e-16f);
    for (int p = rs; p < re; p++) w2[p] *= r;
}

// ---------------- layer 2 aggregation + bias (block = one dst node) ----------------
__global__ void __launch_bounds__(256) k_agg2(const int* rowptr, const int* csr_src,
                                              const float* w2, const float* h2,
                                              const float* b2, float* h2o) {
    int n = blockIdx.x;
    int c = threadIdx.x;
    int rs = rowptr[n], re = rowptr[n + 1];
    float acc = 0.f;
    for (int p = rs; p < re; p++) {
        int s = csr_src[p];
        acc += w2[p] * h2[(size_t)s * 256 + c];
    }
    h2o[(size_t)n * 256 + c] = acc + b2[c];
}

// ---------------- global mean pool ----------------
__global__ void k_pool(const float* h2o, const int* gs, float* out) {
    int g = blockIdx.x >> 3, chunk = blockIdx.x & 7;
    int c = threadIdx.x;
    int s = gs[g], e = gs[g + 1];
    int len = e - s;
    int cs = s + (len * chunk) / 8, ce = s + (len * (chunk + 1)) / 8;
    float acc = 0.f;
    for (int d = cs; d < ce; d++) acc += h2o[(size_t)d * 256 + c];
    float inv = 1.0f / fmaxf((float)len, 1.0f);
    atomicAdd(&out[g * 256 + c], acc * inv);
}

extern "C" void kernel_launch(void* const* d_in, const int* in_sizes, int n_in,
                              void* d_out, int out_size, void* d_ws, size_t ws_size,
                              hipStream_t stream) {
    const float* x    = (const float*)d_in[0];
    const int*   ei   = (const int*)d_in[1];
    const float* ea   = (const float*)d_in[2];
    const int*   batch= (const int*)d_in[3];
    const float* W1   = (const float*)d_in[4];
    const float* We1  = (const float*)d_in[5];
    const float* as1  = (const float*)d_in[6];
    const float* ad1  = (const float*)d_in[7];
    const float* ae1  = (const float*)d_in[8];
    const float* b1   = (const float*)d_in[9];
    const float* W2   = (const float*)d_in[10];
    const float* We2  = (const float*)d_in[11];
    const float* as2  = (const float*)d_in[12];
    const float* ad2  = (const float*)d_in[13];
    const float* ae2  = (const float*)d_in[14];
    const float* b2   = (const float*)d_in[15];
    float* out = (float*)d_out;

    size_t off = 0;
    char* base = (char*)d_ws;
    auto alloc = [&](size_t bytes) -> char* {
        char* p = base + off;
        off += (bytes + 255) & ~(size_t)255;
        return p;
    };
    int*   deg     = (int*)alloc((size_t)NN * 4);
    int*   rowptr  = (int*)alloc((size_t)(NN + 1) * 4);
    int*   cursor  = (int*)alloc((size_t)NN * 4);
    int*   csr_src = (int*)alloc((size_t)E2 * 4);
    float* csr_ea  = (float*)alloc((size_t)E2 * 8);
    float* meansum = (float*)alloc(8);
    float* params  = (float*)alloc(32);
    float* a_s1    = (float*)alloc((size_t)NN * 2 * 4);
    float* a_d1    = (float*)alloc((size_t)NN * 2 * 4);
    float* w1      = (float*)alloc((size_t)E2 * 2 * 4);
    float* h1      = (float*)alloc((size_t)NN * 32 * 4);
    float* h1o     = (float*)alloc((size_t)NN * 32 * 4);
    float* h2      = (float*)alloc((size_t)NN * 256 * 4);
    float* a_s2    = (float*)alloc((size_t)NN * 4);
    float* a_d2    = (float*)alloc((size_t)NN * 4);
    float* w2      = (float*)alloc((size_t)E2 * 4);
    float* h2o     = (float*)alloc((size_t)NN * 256 * 4);
    int*   gs      = (int*)alloc((size_t)(GG + 1) * 4);
    (void)ws_size; (void)in_sizes; (void)n_in; (void)out_size;

    hipMemsetAsync(deg, 0, (size_t)NN * 4, stream);
    hipMemsetAsync(cursor, 0, (size_t)NN * 4, stream);
    hipMemsetAsync(meansum, 0, 8, stream);
    hipMemsetAsync(out, 0, (size_t)GG * 256 * 4, stream);

    k_prep<<<1, 64, 0, stream>>>(We1, ae1, We2, ae2, params);
    k_meansum<<<120, 256, 0, stream>>>(ea, meansum);
    k_deg<<<(E2 + 255) / 256, 256, 0, stream>>>(ei, deg);
    k_scan<<<1, 1024, 0, stream>>>(deg, rowptr);
    k_fill<<<(E2 + 255) / 256, 256, 0, stream>>>(ei, ea, meansum, rowptr, cursor, csr_src, csr_ea);
    k_gs<<<1, 128, 0, stream>>>(batch, gs);

    k_h1<<<(NN * 32) / 256, 256, 0, stream>>>(x, W1, as1, ad1, h1, a_s1, a_d1);
    k_soft1<<<(2 * NN + 255) / 256, 256, 0, stream>>>(rowptr, csr_src, csr_ea, a_s1, a_d1, params, w1);
    k_agg1<<<(NN * 32) / 256, 256, 0, stream>>>(rowptr, csr_src, w1, h1, b1, h1o);

    k_h2<<<NN / 16, 256, 0, stream>>>(h1o, W2, h2);
    k_att2<<<(NN * 64) / 256, 256, 0, stream>>>(h2, as2, ad2, a_s2, a_d2);
    k_soft2<<<(NN + 255) / 256, 256, 0, stream>>>(rowptr, csr_src, csr_ea, a_s2, a_d2, params, w2);
    k_agg2<<<NN, 256, 0, stream>>>(rowptr, csr_src, w2, h2, b2, h2o);

    k_pool<<<GG * 8, 256, 0, stream>>>(h2o, gs, out);
}

// Round 2
// 273.734 us; speedup vs baseline: 1.2647x; 1.2647x over previous
//
#include <hip/hip_runtime.h>
#include <math.h>

#define NN 20000
#define EE 320000
#define E2 340000   // EE + NN self loops
#define GG 64

// ---------------- prep: collapse attention vectors ----------------
// params[0..3]  : ve1[h][i] = sum_c We1[i*32 + h*16 + c] * ae1[h*16+c]
// params[4..5]  : ve2[i]    = sum_c We2[i*256 + c] * ae2[c]
// params[8..39] : vs2[i]    = sum_c W2[i*256 + c] * as2[c]   (i in 0..31)
// params[40..71]: vd2[i]    = sum_c W2[i*256 + c] * ad2[c]
__global__ void k_prep(const float* We1, const float* ae1,
                       const float* We2, const float* ae2,
                       const float* W2, const float* as2, const float* ad2,
                       float* params) {
    int t = threadIdx.x;  // 256 threads
    if (t < 64) {
        float p0 = 0.f, p1 = 0.f;
        for (int c = t; c < 256; c += 64) {
            float a = ae2[c];
            p0 += We2[c] * a;
            p1 += We2[256 + c] * a;
        }
        for (int m = 32; m >= 1; m >>= 1) { p0 += __shfl_xor(p0, m); p1 += __shfl_xor(p1, m); }
        if (t == 0) { params[4] = p0; params[5] = p1; }
        int h = t >> 5, i = (t >> 4) & 1, c = t & 15;
        float p = We1[i * 32 + h * 16 + c] * ae1[h * 16 + c];
        for (int m = 8; m >= 1; m >>= 1) p += __shfl_xor(p, m);
        if ((t & 15) == 0) params[h * 2 + i] = p;
    }
    // vs2/vd2: row i = t>>3, 8 threads per row
    int i = t >> 3, l8 = t & 7;
    float ps = 0.f, pd = 0.f;
    for (int c = l8; c < 256; c += 8) {
        float w = W2[i * 256 + c];
        ps += w * as2[c];
        pd += w * ad2[c];
    }
    for (int m = 4; m >= 1; m >>= 1) { ps += __shfl_xor(ps, m); pd += __shfl_xor(pd, m); }
    if (l8 == 0) { params[8 + i] = ps; params[40 + i] = pd; }
}

// ---------------- mean of edge_attr over E edges ----------------
__global__ void k_meansum(const float* ea, float* meansum) {
    __shared__ float s0[4], s1[4];
    int gid = blockIdx.x * blockDim.x + threadIdx.x;
    int stride = gridDim.x * blockDim.x;
    float a0 = 0.f, a1 = 0.f;
    const float2* ea2 = (const float2*)ea;
    for (int e = gid; e < EE; e += stride) { float2 v = ea2[e]; a0 += v.x; a1 += v.y; }
    for (int m = 32; m >= 1; m >>= 1) { a0 += __shfl_xor(a0, m); a1 += __shfl_xor(a1, m); }
    int lane = threadIdx.x & 63, w = threadIdx.x >> 6;
    if (lane == 0) { s0[w] = a0; s1[w] = a1; }
    __syncthreads();
    if (threadIdx.x == 0) {
        atomicAdd(&meansum[0], s0[0] + s0[1] + s0[2] + s0[3]);
        atomicAdd(&meansum[1], s1[0] + s1[1] + s1[2] + s1[3]);
    }
}

// ---------------- degree histogram over dst ----------------
__global__ void k_deg(const int* ei, int* deg) {
    int t = blockIdx.x * 256 + threadIdx.x;
    if (t >= E2) return;
    int dst = (t < EE) ? ei[EE + t] : (t - EE);
    atomicAdd(&deg[dst], 1);
}

// ---------------- single-block exclusive scan -> rowptr (20/thread) ----------------
__global__ void __launch_bounds__(1024) k_scan(const int* deg, int* rowptr) {
    __shared__ int wsum[16];
    int t = threadIdx.x;  // 1024
    int base = t * 20;
    int loc[20];
    int s = 0;
#pragma unroll
    for (int j = 0; j < 20; j++) {
        int i = base + j;
        int v = (i < NN) ? deg[i] : 0;
        loc[j] = s; s += v;
    }
    int x = s;
    for (int off = 1; off < 64; off <<= 1) {
        int y = __shfl_up(x, off);
        if ((t & 63) >= off) x += y;
    }
    if ((t & 63) == 63) wsum[t >> 6] = x;
    __syncthreads();
    if (t < 16) {
        int ss = wsum[t];
        for (int off = 1; off < 16; off <<= 1) {
            int y = __shfl_up(ss, off);
            if (t >= off) ss += y;
        }
        wsum[t] = ss;
    }
    __syncthreads();
    int pre = (t >= 64) ? wsum[(t >> 6) - 1] : 0;
    int excl = x - s + pre;
#pragma unroll
    for (int j = 0; j < 20; j++) {
        int i = base + j;
        if (i < NN) rowptr[i] = excl + loc[j];
    }
    if (t == 1023) rowptr[NN] = excl + s;
}

// ---------------- CSR fill (src + reordered edge_attr) ----------------
__global__ void k_fill(const int* ei, const float* ea, const float* meansum,
                       const int* rowptr, int* cursor, int* csr_src, float* csr_ea) {
    int t = blockIdx.x * 256 + threadIdx.x;
    if (t >= E2) return;
    int src, dst; float e0, e1;
    if (t < EE) {
        src = ei[t]; dst = ei[EE + t];
        float2 v = ((const float2*)ea)[t];
        e0 = v.x; e1 = v.y;
    } else {
        src = dst = t - EE;
        const float inv = 1.0f / (float)EE;
        e0 = meansum[0] * inv; e1 = meansum[1] * inv;
    }
    int pos = rowptr[dst] + atomicAdd(&cursor[dst], 1);
    csr_src[pos] = src;
    ((float2*)csr_ea)[pos] = make_float2(e0, e1);
}

// ---------------- graph boundaries (batch is sorted) ----------------
__global__ void k_gs(const int* batch, int* gs) {
    int g = threadIdx.x;
    if (g > GG) return;
    if (g == GG) { gs[GG] = NN; return; }
    int lo = 0, hi = NN;
    while (lo < hi) { int mid = (lo + hi) >> 1; if (batch[mid] < g) lo = mid + 1; else hi = mid; }
    gs[g] = lo;
}

// ---------------- layer 1: h1 = x @ W1 ; a_s1, a_d1 ----------------
__global__ void k_h1(const float* x, const float* W1, const float* as1, const float* ad1,
                     float* h1, float* a_s1, float* a_d1) {
    int gid = blockIdx.x * 256 + threadIdx.x;
    if (gid >= NN * 32) return;
    int n = gid >> 5, c = gid & 31;
    float4 xv = ((const float4*)x)[n];
    float acc = xv.x * W1[c] + xv.y * W1[32 + c] + xv.z * W1[64 + c] + xv.w * W1[96 + c];
    h1[gid] = acc;
    float ps = acc * as1[c], pd = acc * ad1[c];
    for (int m = 8; m >= 1; m >>= 1) { ps += __shfl_xor(ps, m); pd += __shfl_xor(pd, m); }
    if ((c & 15) == 0) { int h = c >> 4; a_s1[n * 2 + h] = ps; a_d1[n * 2 + h] = pd; }
}

// ---------------- layer 1 segment softmax ----------------
__global__ void k_soft1(const int* rowptr, const int* csr_src, const float* csr_ea,
                        const float* a_s1, const float* a_d1, const float* params, float* w1) {
    int t = blockIdx.x * 256 + threadIdx.x;
    if (t >= 2 * NN) return;
    int d = t >> 1, h = t & 1;
    int rs = rowptr[d], re = rowptr[d + 1];
    float ad = a_d1[d * 2 + h];
    float vx = params[h * 2 + 0], vy = params[h * 2 + 1];
    float mx = -1e30f;
    for (int p = rs; p < re; p++) {
        int s = csr_src[p];
        float2 e = ((const float2*)csr_ea)[p];
        float al = a_s1[s * 2 + h] + ad + e.x * vx + e.y * vy;
        al = al > 0.f ? al : 0.2f * al;
        w1[p * 2 + h] = al;
        mx = fmaxf(mx, al);
    }
    float sum = 0.f;
    for (int p = rs; p < re; p++) {
        float ex = __expf(w1[p * 2 + h] - mx);
        w1[p * 2 + h] = ex;
        sum += ex;
    }
    float r = 1.0f / (sum + 1e-16f);
    for (int p = rs; p < re; p++) w1[p * 2 + h] *= r;
}

// ---------------- layer 1 aggregation + bias + relu + layer-2 att coeffs ----------------
__global__ void k_agg1(const int* rowptr, const int* csr_src, const float* w1,
                       const float* h1, const float* b1, const float* params,
                       float* h1o, float* a_s2, float* a_d2) {
    int gid = blockIdx.x * 256 + threadIdx.x;
    int n = gid >> 5, c = gid & 31;
    if (n >= NN) return;
    int h = c >> 4;
    int rs = rowptr[n], re = rowptr[n + 1];
    float acc = 0.f;
    for (int p = rs; p < re; p++) {
        int s = csr_src[p];
        acc += w1[p * 2 + h] * h1[s * 32 + c];
    }
    float o = fmaxf(acc + b1[c], 0.f);
    h1o[gid] = o;
    // a_s2[n] = h1o[n,:] . vs2 ; a_d2[n] = h1o[n,:] . vd2  (reduce over 32 lanes)
    float ps = o * params[8 + c], pd = o * params[40 + c];
    for (int m = 16; m >= 1; m >>= 1) { ps += __shfl_xor(ps, m); pd += __shfl_xor(pd, m); }
    if (c == 0) { a_s2[n] = ps; a_d2[n] = pd; }
}

// ---------------- layer 2 segment softmax ----------------
__global__ void k_soft2(const int* rowptr, const int* csr_src, const float* csr_ea,
                        const float* a_s2, const float* a_d2, const float* params, float* w2) {
    int d = blockIdx.x * 256 + threadIdx.x;
    if (d >= NN) return;
    int rs = rowptr[d], re = rowptr[d + 1];
    float ad = a_d2[d];
    float vx = params[4], vy = params[5];
    float mx = -1e30f;
    for (int p = rs; p < re; p++) {
        int s = csr_src[p];
        float2 e = ((const float2*)csr_ea)[p];
        float al = a_s2[s] + ad + e.x * vx + e.y * vy;
        al = al > 0.f ? al : 0.2f * al;
        w2[p] = al;
        mx = fmaxf(mx, al);
    }
    float sum = 0.f;
    for (int p = rs; p < re; p++) { float ex = __expf(w2[p] - mx); w2[p] = ex; sum += ex; }
    float r = 1.0f / (sum + 1e-16f);
    for (int p = rs; p < re; p++) w2[p] *= r;
}

// ---------------- layer 2 aggregation in 32-dim input space ----------------
// out32[d] = sum_e w2[e] * h1o[src_e]   (GEMM with W2 deferred past pooling)
__global__ void k_agg2(const int* rowptr, const int* csr_src, const float* w2,
                       const float* h1o, float* out32) {
    int gid = blockIdx.x * 256 + threadIdx.x;
    int n = gid >> 5, c = gid & 31;
    if (n >= NN) return;
    int rs = rowptr[n], re = rowptr[n + 1];
    float acc = 0.f;
    for (int p = rs; p < re; p++) {
        int s = csr_src[p];
        acc += w2[p] * h1o[s * 32 + c];
    }
    out32[gid] = acc;
}

// ---------------- pool to [G,32] (mean over nodes of each graph) ----------------
__global__ void k_pool32(const float* out32, const int* gs, float* pooled) {
    __shared__ float red[256];
    int g = blockIdx.x;
    int tid = threadIdx.x;
    int c = tid & 31, chunk = tid >> 5;
    int s = gs[g], e = gs[g + 1];
    float acc = 0.f;
    for (int d = s + chunk; d < e; d += 8) acc += out32[d * 32 + c];
    red[tid] = acc;
    __syncthreads();
    if (tid < 32) {
        float v = 0.f;
#pragma unroll
        for (int k = 0; k < 8; k++) v += red[k * 32 + tid];
        int len = e - s;
        pooled[g * 32 + tid] = v / fmaxf((float)len, 1.0f);
    }
}

// ---------------- final tiny GEMM: out = pooled @ W2 + b2 ----------------
__global__ void k_out(const float* pooled, const float* W2, const float* b2, float* out) {
    __shared__ float p[32];
    int g = blockIdx.x, t = threadIdx.x;
    if (t < 32) p[t] = pooled[g * 32 + t];
    __syncthreads();
    float acc = b2[t];
#pragma unroll
    for (int i = 0; i < 32; i++) acc += p[i] * W2[i * 256 + t];
    out[g * 256 + t] = acc;
}

extern "C" void kernel_launch(void* const* d_in, const int* in_sizes, int n_in,
                              void* d_out, int out_size, void* d_ws, size_t ws_size,
                              hipStream_t stream) {
    const float* x    = (const float*)d_in[0];
    const int*   ei   = (const int*)d_in[1];
    const float* ea   = (const float*)d_in[2];
    const int*   batch= (const int*)d_in[3];
    const float* W1   = (const float*)d_in[4];
    const float* We1  = (const float*)d_in[5];
    const float* as1  = (const float*)d_in[6];
    const float* ad1  = (const float*)d_in[7];
    const float* ae1  = (const float*)d_in[8];
    const float* b1   = (const float*)d_in[9];
    const float* W2   = (const float*)d_in[10];
    const float* We2  = (const float*)d_in[11];
    const float* as2  = (const float*)d_in[12];
    const float* ad2  = (const float*)d_in[13];
    const float* ae2  = (const float*)d_in[14];
    const float* b2   = (const float*)d_in[15];
    float* out = (float*)d_out;

    size_t off = 0;
    char* base = (char*)d_ws;
    auto alloc = [&](size_t bytes) -> char* {
        char* p = base + off;
        off += (bytes + 255) & ~(size_t)255;
        return p;
    };
    int*   deg     = (int*)alloc((size_t)NN * 4);
    int*   rowptr  = (int*)alloc((size_t)(NN + 1) * 4);
    int*   cursor  = (int*)alloc((size_t)NN * 4);
    int*   csr_src = (int*)alloc((size_t)E2 * 4);
    float* csr_ea  = (float*)alloc((size_t)E2 * 8);
    float* meansum = (float*)alloc(8);
    float* params  = (float*)alloc(128 * 4);
    float* a_s1    = (float*)alloc((size_t)NN * 2 * 4);
    float* a_d1    = (float*)alloc((size_t)NN * 2 * 4);
    float* w1      = (float*)alloc((size_t)E2 * 2 * 4);
    float* h1      = (float*)alloc((size_t)NN * 32 * 4);
    float* h1o     = (float*)alloc((size_t)NN * 32 * 4);
    float* a_s2    = (float*)alloc((size_t)NN * 4);
    float* a_d2    = (float*)alloc((size_t)NN * 4);
    float* w2      = (float*)alloc((size_t)E2 * 4);
    float* out32   = (float*)alloc((size_t)NN * 32 * 4);
    float* pooled  = (float*)alloc((size_t)GG * 32 * 4);
    int*   gs      = (int*)alloc((size_t)(GG + 1) * 4);
    (void)ws_size; (void)in_sizes; (void)n_in; (void)out_size;

    hipMemsetAsync(deg, 0, (size_t)NN * 4, stream);
    hipMemsetAsync(cursor, 0, (size_t)NN * 4, stream);
    hipMemsetAsync(meansum, 0, 8, stream);

    k_prep<<<1, 256, 0, stream>>>(We1, ae1, We2, ae2, W2, as2, ad2, params);
    k_meansum<<<120, 256, 0, stream>>>(ea, meansum);
    k_deg<<<(E2 + 255) / 256, 256, 0, stream>>>(ei, deg);
    k_scan<<<1, 1024, 0, stream>>>(deg, rowptr);
    k_fill<<<(E2 + 255) / 256, 256, 0, stream>>>(ei, ea, meansum, rowptr, cursor, csr_src, csr_ea);
    k_gs<<<1, 128, 0, stream>>>(batch, gs);

    k_h1<<<(NN * 32) / 256, 256, 0, stream>>>(x, W1, as1, ad1, h1, a_s1, a_d1);
    k_soft1<<<(2 * NN + 255) / 256, 256, 0, stream>>>(rowptr, csr_src, csr_ea, a_s1, a_d1, params, w1);
    k_agg1<<<(NN * 32) / 256, 256, 0, stream>>>(rowptr, csr_src, w1, h1, b1, params, h1o, a_s2, a_d2);

    k_soft2<<<(NN + 255) / 256, 256, 0, stream>>>(rowptr, csr_src, csr_ea, a_s2, a_d2, params, w2);
    k_agg2<<<(NN * 32) / 256, 256, 0, stream>>>(rowptr, csr_src, w2, h1o, out32);

    k_pool32<<<GG, 256, 0, stream>>>(out32, gs, pooled);
    k_out<<<GG, 256, 0, stream>>>(pooled, W2, b2, out);
}

// Round 3
// 205.112 us; speedup vs baseline: 1.6879x; 1.3346x over previous
//
#include <hip/hip_runtime.h>
#include <math.h>

#define NN 20000
#define EE 320000
#define E2 340000   // EE + NN self loops
#define GG 64
#define CAP 96      // per-node LDS edge stash; max degree ~45 for this input
#define SB 240      // setup grid
#define SSTRIDE (SB * 256)

// ---------------- setup: zero deg/cursor, meansum partials, h1 + att1 coeffs,
//                  collapsed params, graph boundaries -------------------------
// params[0..3]  : ve1[h][i] = sum_c We1[i*32 + h*16 + c] * ae1[h*16+c]
// params[4..5]  : ve2[i]    = sum_c We2[i*256 + c] * ae2[c]
// params[8..39] : vs2[i]    = sum_c W2[i*256 + c] * as2[c]
// params[40..71]: vd2[i]    = sum_c W2[i*256 + c] * ad2[c]
__global__ void __launch_bounds__(256) k_setup(
    const float* x, const float* W1, const float* as1, const float* ad1,
    const float* We1, const float* ae1, const float* We2, const float* ae2,
    const float* W2, const float* as2, const float* ad2,
    const float* ea, const int* batch,
    int* deg, int* cursor, float* params, float2* partials, int* gs,
    float* h1, float* a_s1, float* a_d1)
{
    int tid = threadIdx.x, b = blockIdx.x;
    int gid0 = b * 256 + tid;

    // zero deg & cursor (replaces hipMemsetAsync)
    for (int i = gid0; i < NN; i += SSTRIDE) { deg[i] = 0; cursor[i] = 0; }

    // edge_attr mean: per-block partial sums, no atomics
    {
        __shared__ float s0[4], s1[4];
        float a0 = 0.f, a1 = 0.f;
        const float2* ea2 = (const float2*)ea;
        for (int e = gid0; e < EE; e += SSTRIDE) { float2 v = ea2[e]; a0 += v.x; a1 += v.y; }
        for (int m = 32; m >= 1; m >>= 1) { a0 += __shfl_xor(a0, m); a1 += __shfl_xor(a1, m); }
        int lane = tid & 63, w = tid >> 6;
        if (lane == 0) { s0[w] = a0; s1[w] = a1; }
        __syncthreads();
        if (tid == 0)
            partials[b] = make_float2(s0[0] + s0[1] + s0[2] + s0[3],
                                      s1[0] + s1[1] + s1[2] + s1[3]);
    }

    // h1 = x @ W1, a_s1/a_d1  (NN*32 = 640000 elems, multiple of SSTRIDE chunks)
    for (int gid = gid0; gid < NN * 32; gid += SSTRIDE) {
        int n = gid >> 5, c = gid & 31;
        float4 xv = ((const float4*)x)[n];
        float acc = xv.x * W1[c] + xv.y * W1[32 + c] + xv.z * W1[64 + c] + xv.w * W1[96 + c];
        h1[gid] = acc;
        float ps = acc * as1[c], pd = acc * ad1[c];
        for (int m = 8; m >= 1; m >>= 1) { ps += __shfl_xor(ps, m); pd += __shfl_xor(pd, m); }
        if ((c & 15) == 0) { int h = c >> 4; a_s1[n * 2 + h] = ps; a_d1[n * 2 + h] = pd; }
    }

    if (b == 0) {  // collapsed attention params
        int t = tid;
        if (t < 64) {
            float p0 = 0.f, p1 = 0.f;
            for (int c = t; c < 256; c += 64) {
                float a = ae2[c];
                p0 += We2[c] * a;
                p1 += We2[256 + c] * a;
            }
            for (int m = 32; m >= 1; m >>= 1) { p0 += __shfl_xor(p0, m); p1 += __shfl_xor(p1, m); }
            if (t == 0) { params[4] = p0; params[5] = p1; }
            int h = t >> 5, i = (t >> 4) & 1, c = t & 15;
            float p = We1[i * 32 + h * 16 + c] * ae1[h * 16 + c];
            for (int m = 8; m >= 1; m >>= 1) p += __shfl_xor(p, m);
            if ((t & 15) == 0) params[h * 2 + i] = p;
        }
        int i = t >> 3, l8 = t & 7;
        float ps = 0.f, pd = 0.f;
        for (int c = l8; c < 256; c += 8) {
            float w = W2[i * 256 + c];
            ps += w * as2[c];
            pd += w * ad2[c];
        }
        for (int m = 4; m >= 1; m >>= 1) { ps += __shfl_xor(ps, m); pd += __shfl_xor(pd, m); }
        if (l8 == 0) { params[8 + i] = ps; params[40 + i] = pd; }
    }
    if (b == 1 && tid <= GG) {  // graph boundaries (batch sorted)
        int g = tid;
        if (g == GG) gs[GG] = NN;
        else {
            int lo = 0, hi = NN;
            while (lo < hi) { int mid = (lo + hi) >> 1; if (batch[mid] < g) lo = mid + 1; else hi = mid; }
            gs[g] = lo;
        }
    }
}

// ---------------- degree histogram over dst ----------------
__global__ void k_deg(const int* ei, int* deg) {
    int t = blockIdx.x * 256 + threadIdx.x;
    if (t >= E2) return;
    int dst = (t < EE) ? ei[EE + t] : (t - EE);
    atomicAdd(&deg[dst], 1);
}

// ---------------- single-block scan -> rowptr; finalize meansum ----------------
__global__ void __launch_bounds__(1024) k_scan(const int* deg, int* rowptr,
                                               const float2* partials, float* meansum) {
    __shared__ int wsum[16];
    int t = threadIdx.x;
    int base = t * 20;
    int loc[20];
    int s = 0;
#pragma unroll
    for (int j = 0; j < 20; j++) {
        int i = base + j;
        int v = (i < NN) ? deg[i] : 0;
        loc[j] = s; s += v;
    }
    int x = s;
    for (int off = 1; off < 64; off <<= 1) {
        int y = __shfl_up(x, off);
        if ((t & 63) >= off) x += y;
    }
    if ((t & 63) == 63) wsum[t >> 6] = x;
    __syncthreads();
    if (t < 16) {
        int ss = wsum[t];
        for (int off = 1; off < 16; off <<= 1) {
            int y = __shfl_up(ss, off);
            if (t >= off) ss += y;
        }
        wsum[t] = ss;
    }
    __syncthreads();
    int pre = (t >= 64) ? wsum[(t >> 6) - 1] : 0;
    int excl = x - s + pre;
#pragma unroll
    for (int j = 0; j < 20; j++) {
        int i = base + j;
        if (i < NN) rowptr[i] = excl + loc[j];
    }
    if (t == 1023) rowptr[NN] = excl + s;
    // meansum finalize (first wave)
    if (t < 64) {
        float a0 = 0.f, a1 = 0.f;
        for (int i = t; i < SB; i += 64) { float2 v = partials[i]; a0 += v.x; a1 += v.y; }
        for (int m = 32; m >= 1; m >>= 1) { a0 += __shfl_xor(a0, m); a1 += __shfl_xor(a1, m); }
        if (t == 0) { meansum[0] = a0; meansum[1] = a1; }
    }
}

// ---------------- CSR fill ----------------
__global__ void k_fill(const int* ei, const float* ea, const float* meansum,
                       const int* rowptr, int* cursor, int* csr_src, float* csr_ea) {
    int t = blockIdx.x * 256 + threadIdx.x;
    if (t >= E2) return;
    int src, dst; float e0, e1;
    if (t < EE) {
        src = ei[t]; dst = ei[EE + t];
        float2 v = ((const float2*)ea)[t];
        e0 = v.x; e1 = v.y;
    } else {
        src = dst = t - EE;
        const float inv = 1.0f / (float)EE;
        e0 = meansum[0] * inv; e1 = meansum[1] * inv;
    }
    int pos = rowptr[dst] + atomicAdd(&cursor[dst], 1);
    csr_src[pos] = src;
    ((float2*)csr_ea)[pos] = make_float2(e0, e1);
}

// ---------------- layer 1 fused: softmax + aggregate + relu + att2 coeffs ----
// One 32-lane group per dst node; 8 nodes / 256-thread block.
__global__ void __launch_bounds__(256) k_l1(
    const int* rowptr, const int* csr_src, const float* csr_ea,
    const float* a_s1, const float* a_d1, const float* params,
    const float* h1, const float* b1,
    float* h1o, float* a_s2, float* a_d2)
{
    __shared__ int s_src[8][CAP];
    __shared__ float s_w[8][CAP][2];
    int tid = threadIdx.x;
    int g = tid >> 5, lane = tid & 31;
    int n = blockIdx.x * 8 + g;
    if (n >= NN) return;
    int rs = rowptr[n], re = rowptr[n + 1];
    float ad0 = a_d1[n * 2 + 0], ad1v = a_d1[n * 2 + 1];
    float v00 = params[0], v01 = params[1], v10 = params[2], v11 = params[3];
    // pass A: logits -> LDS, running max
    float m0 = -1e30f, m1 = -1e30f;
    for (int p = rs + lane; p < re; p += 32) {
        int s = csr_src[p];
        float2 e = ((const float2*)csr_ea)[p];
        float al0 = a_s1[s * 2 + 0] + ad0 + e.x * v00 + e.y * v01;
        float al1 = a_s1[s * 2 + 1] + ad1v + e.x * v10 + e.y * v11;
        al0 = al0 > 0.f ? al0 : 0.2f * al0;
        al1 = al1 > 0.f ? al1 : 0.2f * al1;
        int idx = p - rs;
        if (idx < CAP) { s_src[g][idx] = s; s_w[g][idx][0] = al0; s_w[g][idx][1] = al1; }
        m0 = fmaxf(m0, al0); m1 = fmaxf(m1, al1);
    }
#pragma unroll
    for (int m = 16; m >= 1; m >>= 1) { m0 = fmaxf(m0, __shfl_xor(m0, m)); m1 = fmaxf(m1, __shfl_xor(m1, m)); }
    // pass B: exp + sum
    float l0 = 0.f, l1 = 0.f;
    for (int p = rs + lane; p < re; p += 32) {
        int idx = p - rs;
        float al0, al1;
        if (idx < CAP) { al0 = s_w[g][idx][0]; al1 = s_w[g][idx][1]; }
        else {
            int s = csr_src[p];
            float2 e = ((const float2*)csr_ea)[p];
            al0 = a_s1[s * 2 + 0] + ad0 + e.x * v00 + e.y * v01;
            al1 = a_s1[s * 2 + 1] + ad1v + e.x * v10 + e.y * v11;
            al0 = al0 > 0.f ? al0 : 0.2f * al0;
            al1 = al1 > 0.f ? al1 : 0.2f * al1;
        }
        float e0 = __expf(al0 - m0), e1 = __expf(al1 - m1);
        if (idx < CAP) { s_w[g][idx][0] = e0; s_w[g][idx][1] = e1; }
        l0 += e0; l1 += e1;
    }
#pragma unroll
    for (int m = 16; m >= 1; m >>= 1) { l0 += __shfl_xor(l0, m); l1 += __shfl_xor(l1, m); }
    // pass C: aggregate (lanes = channels)
    int c = lane, h = lane >> 4;
    float rh = h ? 1.f / (l1 + 1e-16f) : 1.f / (l0 + 1e-16f);
    float mh = h ? m1 : m0;
    float adh = h ? ad1v : ad0;
    float vx = h ? v10 : v00, vy = h ? v11 : v01;
    float acc = 0.f;
    for (int p = rs; p < re; p++) {
        int idx = p - rs;
        int s; float wv;
        if (idx < CAP) { s = s_src[g][idx]; wv = s_w[g][idx][h] * rh; }
        else {
            s = csr_src[p];
            float2 e = ((const float2*)csr_ea)[p];
            float al = a_s1[s * 2 + h] + adh + e.x * vx + e.y * vy;
            al = al > 0.f ? al : 0.2f * al;
            wv = __expf(al - mh) * rh;
        }
        acc += wv * h1[s * 32 + c];
    }
    float o = fmaxf(acc + b1[c], 0.f);
    h1o[n * 32 + c] = o;
    float ps = o * params[8 + c], pd = o * params[40 + c];
#pragma unroll
    for (int m = 16; m >= 1; m >>= 1) { ps += __shfl_xor(ps, m); pd += __shfl_xor(pd, m); }
    if (lane == 0) { a_s2[n] = ps; a_d2[n] = pd; }
}

// ---------------- layer 2 fused: softmax + aggregate (in 32-dim space) -------
__global__ void __launch_bounds__(256) k_l2(
    const int* rowptr, const int* csr_src, const float* csr_ea,
    const float* a_s2, const float* a_d2, const float* params,
    const float* h1o, float* out32)
{
    __shared__ int s_src[8][CAP];
    __shared__ float s_w[8][CAP];
    int tid = threadIdx.x;
    int g = tid >> 5, lane = tid & 31;
    int n = blockIdx.x * 8 + g;
    if (n >= NN) return;
    int rs = rowptr[n], re = rowptr[n + 1];
    float ad = a_d2[n];
    float vx = params[4], vy = params[5];
    float mx = -1e30f;
    for (int p = rs + lane; p < re; p += 32) {
        int s = csr_src[p];
        float2 e = ((const float2*)csr_ea)[p];
        float al = a_s2[s] + ad + e.x * vx + e.y * vy;
        al = al > 0.f ? al : 0.2f * al;
        int idx = p - rs;
        if (idx < CAP) { s_src[g][idx] = s; s_w[g][idx] = al; }
        mx = fmaxf(mx, al);
    }
#pragma unroll
    for (int m = 16; m >= 1; m >>= 1) mx = fmaxf(mx, __shfl_xor(mx, m));
    float lsum = 0.f;
    for (int p = rs + lane; p < re; p += 32) {
        int idx = p - rs;
        float al;
        if (idx < CAP) al = s_w[g][idx];
        else {
            int s = csr_src[p];
            float2 e = ((const float2*)csr_ea)[p];
            al = a_s2[s] + ad + e.x * vx + e.y * vy;
            al = al > 0.f ? al : 0.2f * al;
        }
        float ex = __expf(al - mx);
        if (idx < CAP) s_w[g][idx] = ex;
        lsum += ex;
    }
#pragma unroll
    for (int m = 16; m >= 1; m >>= 1) lsum += __shfl_xor(lsum, m);
    float r = 1.f / (lsum + 1e-16f);
    int c = lane;
    float acc = 0.f;
    for (int p = rs; p < re; p++) {
        int idx = p - rs;
        int s; float wv;
        if (idx < CAP) { s = s_src[g][idx]; wv = s_w[g][idx] * r; }
        else {
            s = csr_src[p];
            float2 e = ((const float2*)csr_ea)[p];
            float al = a_s2[s] + ad + e.x * vx + e.y * vy;
            al = al > 0.f ? al : 0.2f * al;
            wv = __expf(al - mx) * r;
        }
        acc += wv * h1o[s * 32 + c];
    }
    out32[n * 32 + c] = acc;
}

// ---------------- pool to [G,32] then tiny GEMM @ W2 + b2 ----------------
__global__ void __launch_bounds__(256) k_final(
    const float* out32, const int* gs, const float* W2, const float* b2, float* out)
{
    __shared__ float red[256];
    __shared__ float p[32];
    int g = blockIdx.x, tid = threadIdx.x;
    int c = tid & 31, chunk = tid >> 5;
    int s = gs[g], e = gs[g + 1];
    float acc = 0.f;
    for (int d = s + chunk; d < e; d += 8) acc += out32[d * 32 + c];
    red[tid] = acc;
    __syncthreads();
    if (tid < 32) {
        float v = 0.f;
#pragma unroll
        for (int k = 0; k < 8; k++) v += red[k * 32 + tid];
        p[tid] = v / fmaxf((float)(e - s), 1.0f);
    }
    __syncthreads();
    float o = b2[tid];
#pragma unroll
    for (int i = 0; i < 32; i++) o += p[i] * W2[i * 256 + tid];
    out[g * 256 + tid] = o;
}

extern "C" void kernel_launch(void* const* d_in, const int* in_sizes, int n_in,
                              void* d_out, int out_size, void* d_ws, size_t ws_size,
                              hipStream_t stream) {
    const float* x    = (const float*)d_in[0];
    const int*   ei   = (const int*)d_in[1];
    const float* ea   = (const float*)d_in[2];
    const int*   batch= (const int*)d_in[3];
    const float* W1   = (const float*)d_in[4];
    const float* We1  = (const float*)d_in[5];
    const float* as1  = (const float*)d_in[6];
    const float* ad1  = (const float*)d_in[7];
    const float* ae1  = (const float*)d_in[8];
    const float* b1   = (const float*)d_in[9];
    const float* W2   = (const float*)d_in[10];
    const float* We2  = (const float*)d_in[11];
    const float* as2  = (const float*)d_in[12];
    const float* ad2  = (const float*)d_in[13];
    const float* ae2  = (const float*)d_in[14];
    const float* b2   = (const float*)d_in[15];
    float* out = (float*)d_out;

    size_t off = 0;
    char* base = (char*)d_ws;
    auto alloc = [&](size_t bytes) -> char* {
        char* p = base + off;
        off += (bytes + 255) & ~(size_t)255;
        return p;
    };
    int*    deg     = (int*)alloc((size_t)NN * 4);
    int*    rowptr  = (int*)alloc((size_t)(NN + 1) * 4);
    int*    cursor  = (int*)alloc((size_t)NN * 4);
    int*    csr_src = (int*)alloc((size_t)E2 * 4);
    float*  csr_ea  = (float*)alloc((size_t)E2 * 8);
    float*  meansum = (float*)alloc(8);
    float*  params  = (float*)alloc(512);
    float2* partials= (float2*)alloc((size_t)SB * 8);
    float*  a_s1    = (float*)alloc((size_t)NN * 2 * 4);
    float*  a_d1    = (float*)alloc((size_t)NN * 2 * 4);
    float*  h1      = (float*)alloc((size_t)NN * 32 * 4);
    float*  h1o     = (float*)alloc((size_t)NN * 32 * 4);
    float*  a_s2    = (float*)alloc((size_t)NN * 4);
    float*  a_d2    = (float*)alloc((size_t)NN * 4);
    float*  out32   = (float*)alloc((size_t)NN * 32 * 4);
    int*    gs      = (int*)alloc((size_t)(GG + 1) * 4);
    (void)ws_size; (void)in_sizes; (void)n_in; (void)out_size;

    k_setup<<<SB, 256, 0, stream>>>(x, W1, as1, ad1, We1, ae1, We2, ae2,
                                    W2, as2, ad2, ea, batch,
                                    deg, cursor, params, partials, gs, h1, a_s1, a_d1);
    k_deg<<<(E2 + 255) / 256, 256, 0, stream>>>(ei, deg);
    k_scan<<<1, 1024, 0, stream>>>(deg, rowptr, partials, meansum);
    k_fill<<<(E2 + 255) / 256, 256, 0, stream>>>(ei, ea, meansum, rowptr, cursor, csr_src, csr_ea);
    k_l1<<<NN / 8, 256, 0, stream>>>(rowptr, csr_src, csr_ea, a_s1, a_d1, params, h1, b1, h1o, a_s2, a_d2);
    k_l2<<<NN / 8, 256, 0, stream>>>(rowptr, csr_src, csr_ea, a_s2, a_d2, params, h1o, out32);
    k_final<<<GG, 256, 0, stream>>>(out32, gs, W2, b2, out);
}